// Round 3
// baseline (5097.517 us; speedup 1.0000x reference)
//
#include <hip/hip_runtime.h>
#include <hip/hip_bf16.h>

// MnistModelDP: 2-layer LSTM (H=512) over T=64 frames of 128, B=2048, then proj to 10.
// v3: fp16 MFMA, compile-time-K fully-unrolled GEMM (compiler software-pipelines loads),
// layer0(t) + layer1(t-1) paired in one launch for 2x occupancy, packed [W_ih|W_hh],
// fast __expf activations. Cell state fp32; h f16 double-buffered.

typedef _Float16 f16x8 __attribute__((ext_vector_type(8)));
typedef float f32x4 __attribute__((ext_vector_type(4)));

#define Bsz 2048
#define Lsz 8192
#define Tsz 64

__global__ void cvt_f32_f16(const float* __restrict__ src, _Float16* __restrict__ dst, int n4) {
    int stride = gridDim.x * blockDim.x;
    for (int i = blockIdx.x * blockDim.x + threadIdx.x; i < n4; i += stride) {
        float4 v = ((const float4*)src)[i];
        union { _Float16 h[4]; ushort4 u; } o;
        o.h[0] = (_Float16)v.x; o.h[1] = (_Float16)v.y;
        o.h[2] = (_Float16)v.z; o.h[3] = (_Float16)v.w;
        ((ushort4*)dst)[i] = o.u;
    }
}

// pack [2048, K1] W_ih (f32) and [2048, 512] W_hh (f32) -> [2048, K1+512] f16
__global__ void pack_w(const float* __restrict__ Wih, const float* __restrict__ Whh,
                       _Float16* __restrict__ dst, int K1) {
    int KT = K1 + 512;
    int n4 = 2048 * KT / 4;
    int stride = gridDim.x * blockDim.x;
    for (int i = blockIdx.x * blockDim.x + threadIdx.x; i < n4; i += stride) {
        int row = i / (KT / 4);
        int col = (i % (KT / 4)) * 4;
        const float* s = (col < K1) ? (Wih + (size_t)row * K1 + col)
                                    : (Whh + (size_t)row * 512 + (col - K1));
        float4 v = *(const float4*)s;
        union { _Float16 h[4]; ushort4 u; } o;
        o.h[0] = (_Float16)v.x; o.h[1] = (_Float16)v.y;
        o.h[2] = (_Float16)v.z; o.h[3] = (_Float16)v.w;
        ((ushort4*)dst)[i] = o.u;
    }
}

__device__ __forceinline__ float fsig(float x) {
    return 1.0f / (1.0f + __expf(-x));
}
__device__ __forceinline__ float ftanh(float x) {
    // 1 - 2/(e^{2x}+1): monotone, correct limits at +-inf, no inf/inf.
    return 1.0f - 2.0f / (__expf(2.0f * x) + 1.0f);
}

// One LSTM layer timestep tile: gates = [A1 | A2] @ Wcat^T + bias, then cell update.
// Block: 4 waves; tile = 128 rows x 32 cols x 4 gates. Compile-time K1 => full unroll.
// MFMA 16x16x32 f16 layouts (verified lineage: learn_hip m89/m91):
//   A frag: lane l, elem j -> A[l&15][(l>>4)*8 + j]
//   B frag: lane l, elem j -> W[col=l&15][k=(l>>4)*8+j] (W row-major, K contig)
//   C/D:    lane l, reg r  -> C[(l>>4)*4 + r][l&15]
template<int K1>
__device__ __forceinline__ void step_tile(
    const _Float16* __restrict__ A1, int lda1,   // [2048, K1] rows (col window), row stride lda1
    const _Float16* __restrict__ Wcat,            // [2048, K1+512] f16
    const _Float16* __restrict__ A2,              // [2048, 512] f16 (h_prev)
    const float* __restrict__ bias,               // [2048] f32
    float* __restrict__ c,                        // [2048, 512] f32 in/out
    _Float16* __restrict__ h_out,                 // [2048, 512] f16
    int rowblk)                                   // 0..15
{
    constexpr int KT = K1 + 512;
    constexpr int NIT = KT / 32;
    const int lane = threadIdx.x & 63;
    const int w    = threadIdx.x >> 6;
    const int llo  = lane & 15;
    const int lhi  = lane >> 4;
    const int rowW = rowblk * 128 + w * 32;
    const int gc0  = blockIdx.y * 32;

    f32x4 acc[4][2][2] = {};

    float bz[4][2];
#pragma unroll
    for (int g = 0; g < 4; ++g)
#pragma unroll
        for (int gi = 0; gi < 2; ++gi)
            bz[g][gi] = bias[512 * g + gc0 + 16 * gi + llo];

    // per-lane row base pointers (hoisted address math)
    const _Float16* wrow[4][2];
#pragma unroll
    for (int g = 0; g < 4; ++g)
#pragma unroll
        for (int gi = 0; gi < 2; ++gi)
            wrow[g][gi] = Wcat + (size_t)(512 * g + gc0 + 16 * gi + llo) * KT + lhi * 8;
    const _Float16* a1row[2];
    const _Float16* a2row[2];
#pragma unroll
    for (int mi = 0; mi < 2; ++mi) {
        a1row[mi] = A1 + (size_t)(rowW + 16 * mi + llo) * lda1 + lhi * 8;
        a2row[mi] = A2 + (size_t)(rowW + 16 * mi + llo) * 512  + lhi * 8;
    }

#pragma unroll
    for (int kv = 0; kv < NIT; ++kv) {
        const int k0 = kv * 32;
        f16x8 a[2], b[4][2];
#pragma unroll
        for (int mi = 0; mi < 2; ++mi)
            a[mi] = (k0 < K1) ? *(const f16x8*)(a1row[mi] + k0)
                              : *(const f16x8*)(a2row[mi] + (k0 - K1));
#pragma unroll
        for (int g = 0; g < 4; ++g)
#pragma unroll
            for (int gi = 0; gi < 2; ++gi)
                b[g][gi] = *(const f16x8*)(wrow[g][gi] + k0);
#pragma unroll
        for (int g = 0; g < 4; ++g)
#pragma unroll
            for (int mi = 0; mi < 2; ++mi)
#pragma unroll
                for (int gi = 0; gi < 2; ++gi)
                    acc[g][mi][gi] = __builtin_amdgcn_mfma_f32_16x16x32_f16(
                        a[mi], b[g][gi], acc[g][mi][gi], 0, 0, 0);
    }

    // fused cell update epilogue
#pragma unroll
    for (int mi = 0; mi < 2; ++mi) {
#pragma unroll
        for (int gi = 0; gi < 2; ++gi) {
            const int col = gc0 + 16 * gi + llo;
#pragma unroll
            for (int r = 0; r < 4; ++r) {
                const int row = rowW + 16 * mi + lhi * 4 + r;
                float iv = acc[0][mi][gi][r] + bz[0][gi];
                float fv = acc[1][mi][gi][r] + bz[1][gi];
                float gv = acc[2][mi][gi][r] + bz[2][gi];
                float ov = acc[3][mi][gi][r] + bz[3][gi];
                size_t idx = (size_t)row * 512 + col;
                float co = c[idx];
                float cn = fsig(fv) * co + fsig(iv) * ftanh(gv);
                float hn = fsig(ov) * ftanh(cn);
                c[idx] = cn;
                h_out[idx] = (_Float16)hn;
            }
        }
    }
}

// One "round": layer0 step t0 (blocks x<16) and layer1 step t1 = t0-1 (blocks x>=16),
// independent given previous rounds completed. t<0 disables that half.
__global__ __launch_bounds__(256, 2) void lstm_round(
    int t0, int t1,
    const _Float16* __restrict__ xb16,
    const _Float16* __restrict__ Wc0, const float* __restrict__ b0, float* __restrict__ c0,
    _Float16* __restrict__ h00, _Float16* __restrict__ h01,
    const _Float16* __restrict__ Wc1, const float* __restrict__ b1, float* __restrict__ c1,
    _Float16* __restrict__ h10, _Float16* __restrict__ h11)
{
    const int bx = blockIdx.x;
    if (bx < 16) {
        if (t0 < 0) return;
        const _Float16* hr = (t0 & 1) ? h01 : h00;   // reads h0[t0&1]
        _Float16*       hw = (t0 & 1) ? h00 : h01;   // writes h0[(t0+1)&1]
        step_tile<128>(xb16 + (size_t)t0 * 128, Lsz, Wc0, hr, b0, c0, hw, bx);
    } else {
        if (t1 < 0) return;
        const _Float16* h0in = ((t1 + 1) & 1) ? h01 : h00;  // h0 output of step t1
        const _Float16* hr   = (t1 & 1) ? h11 : h10;
        _Float16*       hw   = (t1 & 1) ? h10 : h11;
        step_tile<512>(h0in, 512, Wc1, hr, b1, c1, hw, bx - 16);
    }
}

__global__ void proj_kernel(const _Float16* __restrict__ h1,
                            const float* __restrict__ Wout,  // [10, 512]
                            const float* __restrict__ bout,  // [10]
                            float* __restrict__ out)         // [2048, 10]
{
    int tid = blockIdx.x * blockDim.x + threadIdx.x;
    if (tid >= Bsz * 10) return;
    int b = tid / 10, o = tid % 10;
    float s = bout[o];
    const _Float16* hrow = h1 + (size_t)b * 512;
    const float* wrow = Wout + (size_t)o * 512;
    for (int k = 0; k < 512; ++k) s += (float)hrow[k] * wrow[k];
    out[tid] = s;
}

extern "C" void kernel_launch(void* const* d_in, const int* in_sizes, int n_in,
                              void* d_out, int out_size, void* d_ws, size_t ws_size,
                              hipStream_t stream) {
    const float* xb    = (const float*)d_in[0];
    const float* W_ih0 = (const float*)d_in[1];
    const float* W_hh0 = (const float*)d_in[2];
    const float* b0    = (const float*)d_in[3];
    const float* W_ih1 = (const float*)d_in[4];
    const float* W_hh1 = (const float*)d_in[5];
    const float* b1    = (const float*)d_in[6];
    const float* W_out = (const float*)d_in[7];
    const float* b_out = (const float*)d_in[8];
    float* out = (float*)d_out;

    char* ws = (char*)d_ws;
    size_t off = 0;
    auto alloc = [&](size_t bytes) -> void* {
        void* p = ws + off;
        off += (bytes + 255) & ~(size_t)255;
        return p;
    };
    _Float16* xb16 = (_Float16*)alloc((size_t)Bsz * Lsz * 2);
    _Float16* Wc0  = (_Float16*)alloc((size_t)2048 * 640 * 2);
    _Float16* Wc1  = (_Float16*)alloc((size_t)2048 * 1024 * 2);
    _Float16* h00  = (_Float16*)alloc((size_t)Bsz * 512 * 2);
    _Float16* h01  = (_Float16*)alloc((size_t)Bsz * 512 * 2);
    _Float16* h10  = (_Float16*)alloc((size_t)Bsz * 512 * 2);
    _Float16* h11  = (_Float16*)alloc((size_t)Bsz * 512 * 2);
    float* c0 = (float*)alloc((size_t)Bsz * 512 * 4);
    float* c1 = (float*)alloc((size_t)Bsz * 512 * 4);

    cvt_f32_f16<<<2048, 256, 0, stream>>>(xb, xb16, Bsz * Lsz / 4);
    pack_w<<<1280, 256, 0, stream>>>(W_ih0, W_hh0, Wc0, 128);
    pack_w<<<2048, 256, 0, stream>>>(W_ih1, W_hh1, Wc1, 512);

    hipMemsetAsync(h00, 0, (size_t)Bsz * 512 * 2, stream);
    hipMemsetAsync(h10, 0, (size_t)Bsz * 512 * 2, stream);
    hipMemsetAsync(c0, 0, (size_t)Bsz * 512 * 4, stream);
    hipMemsetAsync(c1, 0, (size_t)Bsz * 512 * 4, stream);

    dim3 grid(32, 16);
    for (int r = 0; r <= Tsz; ++r) {
        int t0 = (r < Tsz) ? r : -1;
        int t1 = r - 1;
        lstm_round<<<grid, 256, 0, stream>>>(t0, t1,
            xb16, Wc0, b0, c0, h00, h01,
            Wc1, b1, c1, h10, h11);
    }

    // final h1 (step 63) was written to h10 ((63+1)&1 == 0)
    proj_kernel<<<(Bsz * 10 + 255) / 256, 256, 0, stream>>>(h10, W_out, b_out, out);
}

// Round 4
// 1784.492 us; speedup vs baseline: 2.8566x; 2.8566x over previous
//
#include <hip/hip_runtime.h>
#include <hip/hip_bf16.h>

// MnistModelDP: 2-layer LSTM (H=512) over T=64 frames of 128, B=2048, then proj to 10.
// v4: m97-style LDS-staged fp16 MFMA step GEMM (global_load_lds width=16, XOR-swizzled
// LDS, 128-row x 32-hcol x 4-gate tile, 4 waves), fused cell update, paired
// layer0(t)/layer1(t-1) rounds, XCD-pinned weight/c slices via block-index decode.

typedef _Float16 f16x8 __attribute__((ext_vector_type(8)));
typedef float f32x4 __attribute__((ext_vector_type(4)));

#define Bsz 2048
#define Lsz 8192
#define Tsz 64

__global__ void cvt_f32_f16(const float* __restrict__ src, _Float16* __restrict__ dst, int n4) {
    int stride = gridDim.x * blockDim.x;
    for (int i = blockIdx.x * blockDim.x + threadIdx.x; i < n4; i += stride) {
        float4 v = ((const float4*)src)[i];
        union { _Float16 h[4]; ushort4 u; } o;
        o.h[0] = (_Float16)v.x; o.h[1] = (_Float16)v.y;
        o.h[2] = (_Float16)v.z; o.h[3] = (_Float16)v.w;
        ((ushort4*)dst)[i] = o.u;
    }
}

// pack [2048, K1] W_ih (f32) and [2048, 512] W_hh (f32) -> [2048, K1+512] f16
__global__ void pack_w(const float* __restrict__ Wih, const float* __restrict__ Whh,
                       _Float16* __restrict__ dst, int K1) {
    int KT = K1 + 512;
    int n4 = 2048 * KT / 4;
    int stride = gridDim.x * blockDim.x;
    for (int i = blockIdx.x * blockDim.x + threadIdx.x; i < n4; i += stride) {
        int row = i / (KT / 4);
        int col = (i % (KT / 4)) * 4;
        const float* s = (col < K1) ? (Wih + (size_t)row * K1 + col)
                                    : (Whh + (size_t)row * 512 + (col - K1));
        float4 v = *(const float4*)s;
        union { _Float16 h[4]; ushort4 u; } o;
        o.h[0] = (_Float16)v.x; o.h[1] = (_Float16)v.y;
        o.h[2] = (_Float16)v.z; o.h[3] = (_Float16)v.w;
        ((ushort4*)dst)[i] = o.u;
    }
}

__device__ __forceinline__ float fsig(float x)  { return 1.0f / (1.0f + __expf(-x)); }
__device__ __forceinline__ float ftanh(float x) { return 1.0f - 2.0f / (__expf(2.0f * x) + 1.0f); }

// One LSTM step tile. Block: 256 thr / 4 waves; tile = 128 batch rows x (32 hcols x 4 gates).
// Wave (wx=w&1, wy=w>>1): rows [wx*64,+64), hcols [wy*16,+16), all 4 gates.
// LDS: A[128][64] f16, B[128][64] f16 (B rows j = gate*32 + local hcol), both stored with
// granule swizzle: LDS[row][slot s] holds col-granule (s ^ (row&7)) -- written by
// pre-swizzling the global_load_lds SOURCE address (linear dest), read with matching XOR.
// MFMA 16x16x32 f16 layouts (verified lineage: v2 kernel passed; learn_hip m89/m91):
//   A frag: lane l elem j -> A[l&15][(l>>4)*8+j] ; B frag: lane l elem j -> W[l&15][(l>>4)*8+j]
//   C/D: lane l reg r -> C[(l>>4)*4+r][l&15]
template<int K1>
__device__ __forceinline__ void step_tile_lds(
    const _Float16* __restrict__ A1, int lda1,   // k < K1 activations
    const _Float16* __restrict__ A2,              // k >= K1 activations (h_prev), ld 512
    const _Float16* __restrict__ Wcat,            // [2048][K1+512]
    const float* __restrict__ bias,               // [2048]
    float* __restrict__ c,                        // [2048][512] fp32 in/out
    _Float16* __restrict__ h_out,                 // [2048][512] f16
    int rowblk, int hcb, char* lA, char* lB)
{
    constexpr int KT  = K1 + 512;
    constexpr int NIT = KT / 64;
    const int tid = threadIdx.x;
    const int ln  = tid & 63;
    const int wv  = tid >> 6;
    const int llo = ln & 15, lhi = ln >> 4;
    const int wx  = wv & 1,  wy  = wv >> 1;
    const int hc0 = hcb * 32;
    const int col = hc0 + wy * 16 + llo;

    // staging lane constants: dest byte (within wave-q 1KB region) = lane*16
    // -> row_sub = ln>>3 (0..7), slot = ln&7; source granule = slot ^ (row&7) = slot ^ row_sub
    const int rsub = ln >> 3;
    const int cg8  = ((ln & 7) ^ rsub) * 8;  // source col offset (f16 elems)

    f32x4 acc[4][4] = {};  // [gate][mi]

    float bz[4];
#pragma unroll
    for (int g = 0; g < 4; ++g) bz[g] = bias[512 * g + col];

    for (int it = 0; it < NIT; ++it) {
        const int k0 = it * 64;
#pragma unroll
        for (int q = 0; q < 4; ++q) {
            const int row  = wv * 32 + q * 8 + rsub;   // tile row 0..127 (row&7 == rsub)
            const int kcol = k0 + cg8;
            // A tile
            const int brow = rowblk * 128 + row;
            const _Float16* srcA = (kcol < K1)
                ? (A1 + (size_t)brow * lda1 + kcol)
                : (A2 + (size_t)brow * 512 + (kcol - K1));
            __builtin_amdgcn_global_load_lds(
                (const __attribute__((address_space(1))) void*)srcA,
                (__attribute__((address_space(3))) void*)(lA + wv * 4096 + q * 1024),
                16, 0, 0);
            // B tile: j = row -> W row = (j>>5)*512 + hc0 + (j&31)
            const int wrow = ((row >> 5) << 9) + hc0 + (row & 31);
            const _Float16* srcB = Wcat + (size_t)wrow * KT + kcol;
            __builtin_amdgcn_global_load_lds(
                (const __attribute__((address_space(1))) void*)srcB,
                (__attribute__((address_space(3))) void*)(lB + wv * 4096 + q * 1024),
                16, 0, 0);
        }
        __syncthreads();  // drains vmcnt before barrier

#pragma unroll
        for (int ks = 0; ks < 2; ++ks) {
            const int gsw = (((ks * 4 + lhi) ^ (llo & 7)) << 4);  // swizzled granule byte
            f16x8 a[4], b[4];
#pragma unroll
            for (int mi = 0; mi < 4; ++mi)
                a[mi] = *(const f16x8*)(lA + (wx * 64 + 16 * mi + llo) * 128 + gsw);
#pragma unroll
            for (int g = 0; g < 4; ++g)
                b[g] = *(const f16x8*)(lB + (g * 32 + wy * 16 + llo) * 128 + gsw);
#pragma unroll
            for (int g = 0; g < 4; ++g)
#pragma unroll
                for (int mi = 0; mi < 4; ++mi)
                    acc[g][mi] = __builtin_amdgcn_mfma_f32_16x16x32_f16(
                        a[mi], b[g], acc[g][mi], 0, 0, 0);
        }
        __syncthreads();
    }

    // fused cell update
#pragma unroll
    for (int mi = 0; mi < 4; ++mi) {
#pragma unroll
        for (int r = 0; r < 4; ++r) {
            const int row = rowblk * 128 + wx * 64 + 16 * mi + lhi * 4 + r;
            float iv = acc[0][mi][r] + bz[0];
            float fv = acc[1][mi][r] + bz[1];
            float gv = acc[2][mi][r] + bz[2];
            float ov = acc[3][mi][r] + bz[3];
            size_t idx = (size_t)row * 512 + col;
            float co = c[idx];
            float cn = fsig(fv) * co + fsig(iv) * ftanh(gv);
            float hn = fsig(ov) * ftanh(cn);
            c[idx] = cn;
            h_out[idx] = (_Float16)hn;
        }
    }
}

// Paired round: layer0 step t0 and layer1 step t1 = t0-1 (independent).
// Block decode pins (layer, hcolblk) group to XCD (bid%8) for weight/c L2 residency:
// bid = gq*128 + rowblk*8 + gr ; group = gq*8+gr in [0,32): layer = group>>4, hcb = group&15.
__global__ __launch_bounds__(256, 2) void lstm_round(
    int t0, int t1,
    const _Float16* __restrict__ xb16,
    const _Float16* __restrict__ Wc0, const float* __restrict__ b0, float* __restrict__ c0,
    _Float16* __restrict__ h00, _Float16* __restrict__ h01,
    const _Float16* __restrict__ Wc1, const float* __restrict__ b1, float* __restrict__ c1,
    _Float16* __restrict__ h10, _Float16* __restrict__ h11)
{
    __shared__ __align__(16) char lA[16384];
    __shared__ __align__(16) char lB[16384];
    const int bid    = blockIdx.x;
    const int gr     = bid & 7;
    const int rowblk = (bid >> 3) & 15;
    const int gq     = bid >> 7;
    const int grp    = gq * 8 + gr;
    const int hcb    = grp & 15;

    if (grp < 16) {
        if (t0 < 0) return;
        const _Float16* hr = (t0 & 1) ? h01 : h00;
        _Float16*       hw = (t0 & 1) ? h00 : h01;
        step_tile_lds<128>(xb16 + (size_t)t0 * 128, Lsz, hr, Wc0, b0, c0, hw, rowblk, hcb, lA, lB);
    } else {
        if (t1 < 0) return;
        const _Float16* h0in = ((t1 + 1) & 1) ? h01 : h00;
        const _Float16* hr   = (t1 & 1) ? h11 : h10;
        _Float16*       hw   = (t1 & 1) ? h10 : h11;
        step_tile_lds<512>(h0in, 512, hr, Wc1, b1, c1, hw, rowblk, hcb, lA, lB);
    }
}

__global__ void proj_kernel(const _Float16* __restrict__ h1,
                            const float* __restrict__ Wout,  // [10, 512]
                            const float* __restrict__ bout,  // [10]
                            float* __restrict__ out)         // [2048, 10]
{
    int tid = blockIdx.x * blockDim.x + threadIdx.x;
    if (tid >= Bsz * 10) return;
    int b = tid / 10, o = tid % 10;
    float s = bout[o];
    const _Float16* hrow = h1 + (size_t)b * 512;
    const float* wrow = Wout + (size_t)o * 512;
    for (int k = 0; k < 512; ++k) s += (float)hrow[k] * wrow[k];
    out[tid] = s;
}

extern "C" void kernel_launch(void* const* d_in, const int* in_sizes, int n_in,
                              void* d_out, int out_size, void* d_ws, size_t ws_size,
                              hipStream_t stream) {
    const float* xb    = (const float*)d_in[0];
    const float* W_ih0 = (const float*)d_in[1];
    const float* W_hh0 = (const float*)d_in[2];
    const float* b0    = (const float*)d_in[3];
    const float* W_ih1 = (const float*)d_in[4];
    const float* W_hh1 = (const float*)d_in[5];
    const float* b1    = (const float*)d_in[6];
    const float* W_out = (const float*)d_in[7];
    const float* b_out = (const float*)d_in[8];
    float* out = (float*)d_out;

    char* ws = (char*)d_ws;
    size_t off = 0;
    auto alloc = [&](size_t bytes) -> void* {
        void* p = ws + off;
        off += (bytes + 255) & ~(size_t)255;
        return p;
    };
    _Float16* xb16 = (_Float16*)alloc((size_t)Bsz * Lsz * 2);
    _Float16* Wc0  = (_Float16*)alloc((size_t)2048 * 640 * 2);
    _Float16* Wc1  = (_Float16*)alloc((size_t)2048 * 1024 * 2);
    _Float16* h00  = (_Float16*)alloc((size_t)Bsz * 512 * 2);
    _Float16* h01  = (_Float16*)alloc((size_t)Bsz * 512 * 2);
    _Float16* h10  = (_Float16*)alloc((size_t)Bsz * 512 * 2);
    _Float16* h11  = (_Float16*)alloc((size_t)Bsz * 512 * 2);
    float* c0 = (float*)alloc((size_t)Bsz * 512 * 4);
    float* c1 = (float*)alloc((size_t)Bsz * 512 * 4);

    cvt_f32_f16<<<2048, 256, 0, stream>>>(xb, xb16, Bsz * Lsz / 4);
    pack_w<<<1280, 256, 0, stream>>>(W_ih0, W_hh0, Wc0, 128);
    pack_w<<<2048, 256, 0, stream>>>(W_ih1, W_hh1, Wc1, 512);

    hipMemsetAsync(h00, 0, (size_t)Bsz * 512 * 2, stream);
    hipMemsetAsync(h10, 0, (size_t)Bsz * 512 * 2, stream);
    hipMemsetAsync(c0, 0, (size_t)Bsz * 512 * 4, stream);
    hipMemsetAsync(c1, 0, (size_t)Bsz * 512 * 4, stream);

    for (int r = 0; r <= Tsz; ++r) {
        int t0 = (r < Tsz) ? r : -1;
        int t1 = r - 1;
        lstm_round<<<dim3(512), 256, 0, stream>>>(t0, t1,
            xb16, Wc0, b0, c0, h00, h01,
            Wc1, b1, c1, h10, h11);
    }

    // final h1 (step 63) written to h1b[(63+1)&1] == h10
    proj_kernel<<<(Bsz * 10 + 255) / 256, 256, 0, stream>>>(h10, W_out, b_out, out);
}

// Round 6
// 1756.471 us; speedup vs baseline: 2.9021x; 1.0160x over previous
//
#include <hip/hip_runtime.h>
#include <hip/hip_bf16.h>

// MnistModelDP: 2-layer LSTM (H=512) over T=64 frames of 128, B=2048, then proj to 10.
// v5: wide-column tiles (128 hcols/group -> 1 group per XCD, halves A-panel fabric dup),
// double-buffered 2-phase K-loop (stage(it+1) issued before compute(it) -> latency hidden),
// 512-thr blocks (8 waves x 64x64 wave-tile), LDS gates-exchange for fused cell update.
// fp16 MFMA 16x16x32, fp32 accum, c fp32 global, h f16 double-buffered.

typedef _Float16 f16x8 __attribute__((ext_vector_type(8)));
typedef float f32x4 __attribute__((ext_vector_type(4)));

#define Bsz 2048
#define Lsz 8192
#define Tsz 64

__global__ void cvt_f32_f16(const float* __restrict__ src, _Float16* __restrict__ dst, int n4) {
    int stride = gridDim.x * blockDim.x;
    for (int i = blockIdx.x * blockDim.x + threadIdx.x; i < n4; i += stride) {
        float4 v = ((const float4*)src)[i];
        union { _Float16 h[4]; ushort4 u; } o;
        o.h[0] = (_Float16)v.x; o.h[1] = (_Float16)v.y;
        o.h[2] = (_Float16)v.z; o.h[3] = (_Float16)v.w;
        ((ushort4*)dst)[i] = o.u;
    }
}

// pack [2048, K1] W_ih (f32) and [2048, 512] W_hh (f32) -> [2048, K1+512] f16
__global__ void pack_w(const float* __restrict__ Wih, const float* __restrict__ Whh,
                       _Float16* __restrict__ dst, int K1) {
    int KT = K1 + 512;
    int n4 = 2048 * KT / 4;
    int stride = gridDim.x * blockDim.x;
    for (int i = blockIdx.x * blockDim.x + threadIdx.x; i < n4; i += stride) {
        int row = i / (KT / 4);
        int col = (i % (KT / 4)) * 4;
        const float* s = (col < K1) ? (Wih + (size_t)row * K1 + col)
                                    : (Whh + (size_t)row * 512 + (col - K1));
        float4 v = *(const float4*)s;
        union { _Float16 h[4]; ushort4 u; } o;
        o.h[0] = (_Float16)v.x; o.h[1] = (_Float16)v.y;
        o.h[2] = (_Float16)v.z; o.h[3] = (_Float16)v.w;
        ((ushort4*)dst)[i] = o.u;
    }
}

__device__ __forceinline__ float fsig(float x)  { return 1.0f / (1.0f + __expf(-x)); }
__device__ __forceinline__ float ftanh(float x) { return 1.0f - 2.0f / (__expf(2.0f * x) + 1.0f); }

// Stage one BK=64 K-slice of B (512 gaterows x 64) + A (64 rows x 64) into LDS at dst.
// LDS rows are 128 B; slot s of row r holds source col-granule (s ^ (r&7)) (16B granules):
// written via pre-swizzled SOURCE address with linear global_load_lds dest (rule #21).
template<int K1>
__device__ __forceinline__ void stage_tiles(
    const _Float16* __restrict__ A1, int lda1,
    const _Float16* __restrict__ A2,
    const _Float16* __restrict__ Wcat,
    int grpc, int rowblk, int k0, char* dst, int tid)
{
    constexpr int KT = K1 + 512;
    const int wv = tid >> 6;
    // B tile: 64 KB = 8 loads x 512 thr x 16 B. dest byte q*8192 + tid*16 -> LDS row j.
#pragma unroll
    for (int q = 0; q < 8; ++q) {
        const int j  = q * 64 + (tid >> 3);                  // B-LDS row = block gate-col
        const int cg = (((tid & 7) ^ (j & 7)) << 3);         // source granule col (f16 units)
        const int wrow = ((j >> 7) << 9) + grpc * 128 + (j & 127);  // gate*512 + grpc*128 + lc
        const _Float16* src = Wcat + (size_t)wrow * KT + k0 + cg;
        __builtin_amdgcn_global_load_lds(
            (const __attribute__((address_space(1))) void*)src,
            (__attribute__((address_space(3))) void*)(dst + q * 8192 + wv * 1024),
            16, 0, 0);
    }
    // A tile: 8 KB = 1 load x 512 thr x 16 B at offset 65536.
    {
        const int row  = tid >> 3;
        const int cg   = (((tid & 7) ^ (row & 7)) << 3);
        const int kcol = k0 + cg;
        const int brow = rowblk * 64 + row;
        const _Float16* src = (kcol < K1)
            ? (A1 + (size_t)brow * lda1 + kcol)
            : (A2 + (size_t)brow * 512 + (kcol - K1));
        __builtin_amdgcn_global_load_lds(
            (const __attribute__((address_space(1))) void*)src,
            (__attribute__((address_space(3))) void*)(dst + 65536 + wv * 1024),
            16, 0, 0);
    }
}

// One LSTM step tile: 64 batch rows x 512 gate-cols (128 hcols x 4 gates), K = K1+512.
// 8 waves; wave wc owns gate-cols [wc*64, wc*64+64): 4 row-frags x 4 col-frags, BK=64.
// MFMA 16x16x32 f16 layouts (passed in v2/v4):
//   A frag: lane l elem j -> A[l&15][(l>>4)*8+j]; B frag: lane l -> W[col l&15][(l>>4)*8+j]
//   C/D: lane l reg r -> C[(l>>4)*4+r][l&15]
template<int K1>
__device__ __forceinline__ void step_tile_v5(
    const _Float16* __restrict__ A1, int lda1,
    const _Float16* __restrict__ A2,
    const _Float16* __restrict__ Wcat,
    const float* __restrict__ bias,
    float* __restrict__ c,
    _Float16* __restrict__ h_out,
    int rowblk, int grpc, char* lds)
{
    constexpr int KT  = K1 + 512;
    constexpr int NIT = KT / 64;
    const int tid = threadIdx.x;
    const int ln  = tid & 63;
    const int wc  = tid >> 6;           // wave id == col-group (64 gate-cols)
    const int llo = ln & 15, lhi = ln >> 4;

    f32x4 acc[4][4] = {};               // [row-frag mi][col-frag cf]

    stage_tiles<K1>(A1, lda1, A2, Wcat, grpc, rowblk, 0, lds, tid);
    __syncthreads();

    for (int it = 0; it < NIT; ++it) {
        char* cur = lds + (it & 1) * 73728;
        if (it + 1 < NIT)   // prefetch next K-slice into other buffer (latency hidden by compute)
            stage_tiles<K1>(A1, lda1, A2, Wcat, grpc, rowblk, (it + 1) * 64,
                            lds + ((it + 1) & 1) * 73728, tid);
#pragma unroll
        for (int ks = 0; ks < 2; ++ks) {
            const int gsw = (((ks * 4 + lhi) ^ (llo & 7)) << 4);   // swizzled granule byte
            f16x8 a[4], b[4];
#pragma unroll
            for (int mi = 0; mi < 4; ++mi)
                a[mi] = *(const f16x8*)(cur + 65536 + (mi * 16 + llo) * 128 + gsw);
#pragma unroll
            for (int cf = 0; cf < 4; ++cf)
                b[cf] = *(const f16x8*)(cur + (wc * 64 + cf * 16 + llo) * 128 + gsw);
#pragma unroll
            for (int mi = 0; mi < 4; ++mi)
#pragma unroll
                for (int cf = 0; cf < 4; ++cf)
                    acc[mi][cf] = __builtin_amdgcn_mfma_f32_16x16x32_f16(
                        a[mi], b[cf], acc[mi][cf], 0, 0, 0);
        }
        __syncthreads();   // drains prefetch (issued ~1 compute-phase ago) + LDS reads
    }

    // gates exchange: acc -> LDS f32 [64 rows][512 cols] (overlays staging buffers; safe
    // after final barrier). col = wc*64+cf*16+llo; gate = col>>7, lc = col&127.
    float* gl = (float*)lds;
#pragma unroll
    for (int mi = 0; mi < 4; ++mi)
#pragma unroll
        for (int cf = 0; cf < 4; ++cf) {
            const int col = wc * 64 + cf * 16 + llo;
#pragma unroll
            for (int r = 0; r < 4; ++r) {
                const int row = mi * 16 + lhi * 4 + r;
                gl[row * 512 + col] = acc[mi][cf][r];
            }
        }
    __syncthreads();

    // fused cell update: 16 elems/thread; lc fixed per thread -> coalesced c/h access.
    const int lc   = tid & 127;
    const int r0   = tid >> 7;          // 0..3
    const int hcol = grpc * 128 + lc;
    float bz[4];
#pragma unroll
    for (int g = 0; g < 4; ++g) bz[g] = bias[g * 512 + hcol];
#pragma unroll
    for (int i = 0; i < 16; ++i) {
        const int row = i * 4 + r0;
        float iv = gl[row * 512 +   0 + lc] + bz[0];
        float fv = gl[row * 512 + 128 + lc] + bz[1];
        float gv = gl[row * 512 + 256 + lc] + bz[2];
        float ov = gl[row * 512 + 384 + lc] + bz[3];
        const size_t idx = (size_t)(rowblk * 64 + row) * 512 + hcol;
        float co = c[idx];
        float cn = fsig(fv) * co + fsig(iv) * ftanh(gv);
        float hn = fsig(ov) * ftanh(cn);
        c[idx] = cn;
        h_out[idx] = (_Float16)hn;
    }
}

// Paired round: grp = bid&7 (one group per XCD): grp 0-3 -> layer0 step t0 (hcol grp),
// grp 4-7 -> layer1 step t1 = t0-1. rowblk = bid>>3 (0..31, BM=64).
__global__ __launch_bounds__(512, 2) void lstm_round(
    int t0, int t1,
    const _Float16* __restrict__ xb16,
    const _Float16* __restrict__ Wc0, const float* __restrict__ b0, float* __restrict__ c0,
    _Float16* __restrict__ h00, _Float16* __restrict__ h01,
    const _Float16* __restrict__ Wc1, const float* __restrict__ b1, float* __restrict__ c1,
    _Float16* __restrict__ h10, _Float16* __restrict__ h11)
{
    __shared__ __align__(16) char lds[147456];
    const int bid    = blockIdx.x;
    const int grp    = bid & 7;
    const int rowblk = bid >> 3;

    if (grp < 4) {
        if (t0 < 0) return;
        const _Float16* hr = (t0 & 1) ? h01 : h00;
        _Float16*       hw = (t0 & 1) ? h00 : h01;
        step_tile_v5<128>(xb16 + (size_t)t0 * 128, Lsz, hr, Wc0, b0, c0, hw, rowblk, grp, lds);
    } else {
        if (t1 < 0) return;
        const _Float16* h0in = ((t1 + 1) & 1) ? h01 : h00;  // h0 output of step t1
        const _Float16* hr   = (t1 & 1) ? h11 : h10;
        _Float16*       hw   = (t1 & 1) ? h10 : h11;
        step_tile_v5<512>(h0in, 512, hr, Wc1, b1, c1, hw, rowblk, grp - 4, lds);
    }
}

__global__ void proj_kernel(const _Float16* __restrict__ h1,
                            const float* __restrict__ Wout,  // [10, 512]
                            const float* __restrict__ bout,  // [10]
                            float* __restrict__ out)         // [2048, 10]
{
    int tid = blockIdx.x * blockDim.x + threadIdx.x;
    if (tid >= Bsz * 10) return;
    int b = tid / 10, o = tid % 10;
    float s = bout[o];
    const _Float16* hrow = h1 + (size_t)b * 512;
    const float* wrow = Wout + (size_t)o * 512;
    for (int k = 0; k < 512; ++k) s += (float)hrow[k] * wrow[k];
    out[tid] = s;
}

extern "C" void kernel_launch(void* const* d_in, const int* in_sizes, int n_in,
                              void* d_out, int out_size, void* d_ws, size_t ws_size,
                              hipStream_t stream) {
    const float* xb    = (const float*)d_in[0];
    const float* W_ih0 = (const float*)d_in[1];
    const float* W_hh0 = (const float*)d_in[2];
    const float* b0    = (const float*)d_in[3];
    const float* W_ih1 = (const float*)d_in[4];
    const float* W_hh1 = (const float*)d_in[5];
    const float* b1    = (const float*)d_in[6];
    const float* W_out = (const float*)d_in[7];
    const float* b_out = (const float*)d_in[8];
    float* out = (float*)d_out;

    char* ws = (char*)d_ws;
    size_t off = 0;
    auto alloc = [&](size_t bytes) -> void* {
        void* p = ws + off;
        off += (bytes + 255) & ~(size_t)255;
        return p;
    };
    _Float16* xb16 = (_Float16*)alloc((size_t)Bsz * Lsz * 2);
    _Float16* Wc0  = (_Float16*)alloc((size_t)2048 * 640 * 2);
    _Float16* Wc1  = (_Float16*)alloc((size_t)2048 * 1024 * 2);
    _Float16* h00  = (_Float16*)alloc((size_t)Bsz * 512 * 2);
    _Float16* h01  = (_Float16*)alloc((size_t)Bsz * 512 * 2);
    _Float16* h10  = (_Float16*)alloc((size_t)Bsz * 512 * 2);
    _Float16* h11  = (_Float16*)alloc((size_t)Bsz * 512 * 2);
    float* c0 = (float*)alloc((size_t)Bsz * 512 * 4);
    float* c1 = (float*)alloc((size_t)Bsz * 512 * 4);

    cvt_f32_f16<<<2048, 256, 0, stream>>>(xb, xb16, Bsz * Lsz / 4);
    pack_w<<<1280, 256, 0, stream>>>(W_ih0, W_hh0, Wc0, 128);
    pack_w<<<2048, 256, 0, stream>>>(W_ih1, W_hh1, Wc1, 512);

    hipMemsetAsync(h00, 0, (size_t)Bsz * 512 * 2, stream);
    hipMemsetAsync(h10, 0, (size_t)Bsz * 512 * 2, stream);
    hipMemsetAsync(c0, 0, (size_t)Bsz * 512 * 4, stream);
    hipMemsetAsync(c1, 0, (size_t)Bsz * 512 * 4, stream);

    for (int r = 0; r <= Tsz; ++r) {
        int t0 = (r < Tsz) ? r : -1;
        int t1 = r - 1;
        lstm_round<<<dim3(256), 512, 0, stream>>>(t0, t1,
            xb16, Wc0, b0, c0, h00, h01,
            Wc1, b1, c1, h10, h11);
    }

    // final h1 (step 63) written to h1b[(63+1)&1] == h10
    proj_kernel<<<(Bsz * 10 + 255) / 256, 256, 0, stream>>>(h10, W_out, b_out, out);
}

// Round 7
// 1667.655 us; speedup vs baseline: 3.0567x; 1.0533x over previous
//
#include <hip/hip_runtime.h>
#include <hip/hip_bf16.h>

// MnistModelDP: 2-layer LSTM (H=512) over T=64 frames of 128, B=2048, then proj to 10.
// v6: square-ish tiles BM=256 x BN=128 (cuts L2 weight re-read 4x vs v5's skinny tiles),
// both layers in one 256-block launch (1 block/CU, 8 waves, wave tile 64x64),
// XCD-pinned col-strips, 2-phase dbuf staging via global_load_lds w=16 + granule-XOR
// swizzle (proven v4/v5), fused cell update via 128KB LDS gates-exchange.
// fp16 MFMA 16x16x32, fp32 accum, c fp32 global, h f16 double-buffered.

typedef _Float16 f16x8 __attribute__((ext_vector_type(8)));
typedef float f32x4 __attribute__((ext_vector_type(4)));

#define Bsz 2048
#define Lsz 8192
#define Tsz 64

__global__ void cvt_f32_f16(const float* __restrict__ src, _Float16* __restrict__ dst, int n4) {
    int stride = gridDim.x * blockDim.x;
    for (int i = blockIdx.x * blockDim.x + threadIdx.x; i < n4; i += stride) {
        float4 v = ((const float4*)src)[i];
        union { _Float16 h[4]; ushort4 u; } o;
        o.h[0] = (_Float16)v.x; o.h[1] = (_Float16)v.y;
        o.h[2] = (_Float16)v.z; o.h[3] = (_Float16)v.w;
        ((ushort4*)dst)[i] = o.u;
    }
}

// pack [2048, K1] W_ih (f32) and [2048, 512] W_hh (f32) -> [2048, K1+512] f16
__global__ void pack_w(const float* __restrict__ Wih, const float* __restrict__ Whh,
                       _Float16* __restrict__ dst, int K1) {
    int KT = K1 + 512;
    int n4 = 2048 * KT / 4;
    int stride = gridDim.x * blockDim.x;
    for (int i = blockIdx.x * blockDim.x + threadIdx.x; i < n4; i += stride) {
        int row = i / (KT / 4);
        int col = (i % (KT / 4)) * 4;
        const float* s = (col < K1) ? (Wih + (size_t)row * K1 + col)
                                    : (Whh + (size_t)row * 512 + (col - K1));
        float4 v = *(const float4*)s;
        union { _Float16 h[4]; ushort4 u; } o;
        o.h[0] = (_Float16)v.x; o.h[1] = (_Float16)v.y;
        o.h[2] = (_Float16)v.z; o.h[3] = (_Float16)v.w;
        ((ushort4*)dst)[i] = o.u;
    }
}

__device__ __forceinline__ float fsig(float x)  { return 1.0f / (1.0f + __expf(-x)); }
__device__ __forceinline__ float ftanh(float x) { return 1.0f - 2.0f / (__expf(2.0f * x) + 1.0f); }

// Stage one BK=64 K-slice: B (128 gate-cols x 64) at buf+0 (16KB), A (256 rows x 64) at
// buf+16384 (32KB). LDS rows 128 B; slot s of row r holds source granule (s ^ (r&7))
// via pre-swizzled SOURCE + linear global_load_lds dest (both-sides rule #21, proven v4/v5).
template<int K1>
__device__ __forceinline__ void stage_v6(
    const _Float16* __restrict__ A1, int lda1,
    const _Float16* __restrict__ A2,
    const _Float16* __restrict__ Wcat,
    int hcb, int rowtile, int k0, char* buf, int tid)
{
    constexpr int KT = K1 + 512;
    const int wv = tid >> 6;
    // B tile: rows j = g*32 + lc -> W row g*512 + hcb*32 + lc
#pragma unroll
    for (int q = 0; q < 2; ++q) {
        const int j  = q * 64 + (tid >> 3);
        const int cg = (((tid & 7) ^ (j & 7)) << 3);
        const int wrow = ((j >> 5) << 9) + hcb * 32 + (j & 31);
        const _Float16* src = Wcat + (size_t)wrow * KT + k0 + cg;
        __builtin_amdgcn_global_load_lds(
            (const __attribute__((address_space(1))) void*)src,
            (__attribute__((address_space(3))) void*)(buf + q * 8192 + wv * 1024),
            16, 0, 0);
    }
    // A tile: 256 rows (k0 uniform-selects A1 vs A2 since cg<64 and K1 % 64 == 0)
#pragma unroll
    for (int q = 0; q < 4; ++q) {
        const int row  = q * 64 + (tid >> 3);
        const int cg   = (((tid & 7) ^ (row & 7)) << 3);
        const int kcol = k0 + cg;
        const int brow = rowtile * 256 + row;
        const _Float16* src = (kcol < K1)
            ? (A1 + (size_t)brow * lda1 + kcol)
            : (A2 + (size_t)brow * 512 + (kcol - K1));
        __builtin_amdgcn_global_load_lds(
            (const __attribute__((address_space(1))) void*)src,
            (__attribute__((address_space(3))) void*)(buf + 16384 + q * 8192 + wv * 1024),
            16, 0, 0);
    }
}

// One LSTM step tile: 256 batch rows x 128 gate-cols (32 hcols x 4 gates), K = K1+512.
// 8 waves as 4(row) x 2(col) grid of 64x64 wave tiles. BK=64, double-buffered staging.
// MFMA 16x16x32 f16 layouts (passed v2/v4/v5):
//   A frag: lane l elem j -> A[l&15][(l>>4)*8+j]; B frag: lane l -> W[col l&15][(l>>4)*8+j]
//   C/D: lane l reg r -> C[(l>>4)*4+r][l&15]
template<int K1>
__device__ __forceinline__ void step_v6(
    const _Float16* __restrict__ A1, int lda1,
    const _Float16* __restrict__ A2,
    const _Float16* __restrict__ Wcat,
    const float* __restrict__ bias,
    float* __restrict__ c,
    _Float16* __restrict__ h_out,
    int rowtile, int hcb, char* lds)
{
    constexpr int KT  = K1 + 512;
    constexpr int NIT = KT / 64;
    const int tid = threadIdx.x;
    const int ln  = tid & 63;
    const int wv  = tid >> 6;
    const int llo = ln & 15, lhi = ln >> 4;
    const int wr  = wv >> 1, wc = wv & 1;   // wave row tile (x64), wave col tile (x64)

    f32x4 acc[4][4] = {};                   // [row-frag mi][col-frag cf]

    stage_v6<K1>(A1, lda1, A2, Wcat, hcb, rowtile, 0, lds, tid);
    __syncthreads();

    for (int it = 0; it < NIT; ++it) {
        char* cur = lds + (it & 1) * 49152;
        if (it + 1 < NIT)   // prefetch next K-slice into other buffer
            stage_v6<K1>(A1, lda1, A2, Wcat, hcb, rowtile, (it + 1) * 64,
                         lds + ((it + 1) & 1) * 49152, tid);
#pragma unroll
        for (int ks = 0; ks < 2; ++ks) {
            const int gsw = (((ks * 4 + lhi) ^ (llo & 7)) << 4);   // swizzled granule byte
            f16x8 a[4], b[4];
#pragma unroll
            for (int mi = 0; mi < 4; ++mi)
                a[mi] = *(const f16x8*)(cur + 16384 + (wr * 64 + mi * 16 + llo) * 128 + gsw);
#pragma unroll
            for (int cf = 0; cf < 4; ++cf)
                b[cf] = *(const f16x8*)(cur + (wc * 64 + cf * 16 + llo) * 128 + gsw);
#pragma unroll
            for (int mi = 0; mi < 4; ++mi)
#pragma unroll
                for (int cf = 0; cf < 4; ++cf)
                    acc[mi][cf] = __builtin_amdgcn_mfma_f32_16x16x32_f16(
                        a[mi], b[cf], acc[mi][cf], 0, 0, 0);
        }
        __syncthreads();
    }

    // gates exchange: acc -> LDS f32 [256 rows][128 cols] (128 KB overlay, safe after barrier)
    float* gl = (float*)lds;
#pragma unroll
    for (int mi = 0; mi < 4; ++mi)
#pragma unroll
        for (int cf = 0; cf < 4; ++cf) {
            const int col = wc * 64 + cf * 16 + llo;
#pragma unroll
            for (int r = 0; r < 4; ++r) {
                const int row = wr * 64 + mi * 16 + lhi * 4 + r;
                gl[row * 128 + col] = acc[mi][cf][r];
            }
        }
    __syncthreads();

    // fused cell update: 16 cells/thread; local col j = g*32 + lc.
    const int lc   = tid & 31;
    const int ro   = tid >> 5;              // 0..15
    const int hcol = hcb * 32 + lc;
    float bz[4];
#pragma unroll
    for (int g = 0; g < 4; ++g) bz[g] = bias[g * 512 + hcol];
#pragma unroll
    for (int i = 0; i < 16; ++i) {
        const int row = i * 16 + ro;
        float iv = gl[row * 128 +  0 + lc] + bz[0];
        float fv = gl[row * 128 + 32 + lc] + bz[1];
        float gv = gl[row * 128 + 64 + lc] + bz[2];
        float ov = gl[row * 128 + 96 + lc] + bz[3];
        const size_t idx = (size_t)(rowtile * 256 + row) * 512 + hcol;
        float co = c[idx];
        float cn = fsig(fv) * co + fsig(iv) * ftanh(gv);
        float hn = fsig(ov) * ftanh(cn);
        c[idx] = cn;
        h_out[idx] = (_Float16)hn;
    }
}

// Paired round, 256 blocks (1/CU). Decode: x = bid&7 (XCD), q = bid>>3 in [0,32):
// layer = q>>4, rowtile = (q>>1)&7, hcb = x*2 + (q&1). Each XCD hosts 2 col-strips of
// each layer (weights + c slices L2-resident), all 8 rowtiles.
__global__ __launch_bounds__(512, 2) void lstm_round(
    int t0, int t1,
    const _Float16* __restrict__ xb16,
    const _Float16* __restrict__ Wc0, const float* __restrict__ b0, float* __restrict__ c0,
    _Float16* __restrict__ h00, _Float16* __restrict__ h01,
    const _Float16* __restrict__ Wc1, const float* __restrict__ b1, float* __restrict__ c1,
    _Float16* __restrict__ h10, _Float16* __restrict__ h11)
{
    __shared__ __align__(16) char lds[131072];
    const int bid     = blockIdx.x;
    const int x       = bid & 7;
    const int q       = bid >> 3;
    const int layer   = q >> 4;
    const int rowtile = (q >> 1) & 7;
    const int hcb     = x * 2 + (q & 1);

    if (layer == 0) {
        if (t0 < 0) return;
        const _Float16* hr = (t0 & 1) ? h01 : h00;
        _Float16*       hw = (t0 & 1) ? h00 : h01;
        step_v6<128>(xb16 + (size_t)t0 * 128, Lsz, hr, Wc0, b0, c0, hw, rowtile, hcb, lds);
    } else {
        if (t1 < 0) return;
        const _Float16* h0in = ((t1 + 1) & 1) ? h01 : h00;  // h0 output of step t1
        const _Float16* hr   = (t1 & 1) ? h11 : h10;
        _Float16*       hw   = (t1 & 1) ? h10 : h11;
        step_v6<512>(h0in, 512, hr, Wc1, b1, c1, hw, rowtile, hcb, lds);
    }
}

__global__ void proj_kernel(const _Float16* __restrict__ h1,
                            const float* __restrict__ Wout,  // [10, 512]
                            const float* __restrict__ bout,  // [10]
                            float* __restrict__ out)         // [2048, 10]
{
    int tid = blockIdx.x * blockDim.x + threadIdx.x;
    if (tid >= Bsz * 10) return;
    int b = tid / 10, o = tid % 10;
    float s = bout[o];
    const _Float16* hrow = h1 + (size_t)b * 512;
    const float* wrow = Wout + (size_t)o * 512;
    for (int k = 0; k < 512; ++k) s += (float)hrow[k] * wrow[k];
    out[tid] = s;
}

extern "C" void kernel_launch(void* const* d_in, const int* in_sizes, int n_in,
                              void* d_out, int out_size, void* d_ws, size_t ws_size,
                              hipStream_t stream) {
    const float* xb    = (const float*)d_in[0];
    const float* W_ih0 = (const float*)d_in[1];
    const float* W_hh0 = (const float*)d_in[2];
    const float* b0    = (const float*)d_in[3];
    const float* W_ih1 = (const float*)d_in[4];
    const float* W_hh1 = (const float*)d_in[5];
    const float* b1    = (const float*)d_in[6];
    const float* W_out = (const float*)d_in[7];
    const float* b_out = (const float*)d_in[8];
    float* out = (float*)d_out;

    char* ws = (char*)d_ws;
    size_t off = 0;
    auto alloc = [&](size_t bytes) -> void* {
        void* p = ws + off;
        off += (bytes + 255) & ~(size_t)255;
        return p;
    };
    _Float16* xb16 = (_Float16*)alloc((size_t)Bsz * Lsz * 2);
    _Float16* Wc0  = (_Float16*)alloc((size_t)2048 * 640 * 2);
    _Float16* Wc1  = (_Float16*)alloc((size_t)2048 * 1024 * 2);
    _Float16* h00  = (_Float16*)alloc((size_t)Bsz * 512 * 2);
    _Float16* h01  = (_Float16*)alloc((size_t)Bsz * 512 * 2);
    _Float16* h10  = (_Float16*)alloc((size_t)Bsz * 512 * 2);
    _Float16* h11  = (_Float16*)alloc((size_t)Bsz * 512 * 2);
    float* c0 = (float*)alloc((size_t)Bsz * 512 * 4);
    float* c1 = (float*)alloc((size_t)Bsz * 512 * 4);

    cvt_f32_f16<<<2048, 256, 0, stream>>>(xb, xb16, Bsz * Lsz / 4);
    pack_w<<<1280, 256, 0, stream>>>(W_ih0, W_hh0, Wc0, 128);
    pack_w<<<2048, 256, 0, stream>>>(W_ih1, W_hh1, Wc1, 512);

    hipMemsetAsync(h00, 0, (size_t)Bsz * 512 * 2, stream);
    hipMemsetAsync(h10, 0, (size_t)Bsz * 512 * 2, stream);
    hipMemsetAsync(c0, 0, (size_t)Bsz * 512 * 4, stream);
    hipMemsetAsync(c1, 0, (size_t)Bsz * 512 * 4, stream);

    for (int r = 0; r <= Tsz; ++r) {
        int t0 = (r < Tsz) ? r : -1;
        int t1 = r - 1;
        lstm_round<<<dim3(256), 512, 0, stream>>>(t0, t1,
            xb16, Wc0, b0, c0, h00, h01,
            Wc1, b1, c1, h10, h11);
    }

    // final h1 (step 63) written to h10
    proj_kernel<<<(Bsz * 10 + 255) / 256, 256, 0, stream>>>(h10, W_out, b_out, out);
}